// Round 1
// baseline (107.309 us; speedup 1.0000x reference)
//
#include <hip/hip_runtime.h>
#include <hip/hip_bf16.h>

#define NTOKENS 500000
#define NSAMPLED 8192
#define NHID 256
#define BATCH 8192
#define LROW 8193  // 1 + NSAMPLED
#define OUT_TAIL ((size_t)BATCH * LROW)  // offset of new_targets

typedef short s16x8 __attribute__((ext_vector_type(8)));
typedef float f32x4 __attribute__((ext_vector_type(4)));
typedef unsigned short u16;

// RNE float->bf16 (inputs are finite; no NaN handling needed)
static __device__ __forceinline__ u16 f2bf(float f) {
  unsigned u = __float_as_uint(f);
  unsigned r = (u + 0x7fffu + ((u >> 16) & 1u)) >> 16;
  return (u16)r;
}

static __device__ __forceinline__ s16x8 pack8(float4 v0, float4 v1) {
  s16x8 o;
  o[0] = (short)f2bf(v0.x); o[1] = (short)f2bf(v0.y);
  o[2] = (short)f2bf(v0.z); o[3] = (short)f2bf(v0.w);
  o[4] = (short)f2bf(v1.x); o[5] = (short)f2bf(v1.y);
  o[6] = (short)f2bf(v1.z); o[7] = (short)f2bf(v1.w);
  return o;
}

// ---- prep A: inputs fp32 -> bf16 [BATCH][NHID] ----
__global__ void k_prep_a(const float* __restrict__ in, u16* __restrict__ outA) {
  size_t idx = ((size_t)blockIdx.x * 256 + threadIdx.x) * 8;
  const float4* p = (const float4*)(in + idx);
  float4 v0 = p[0], v1 = p[1];
  *(s16x8*)(outA + idx) = pack8(v0, v1);
}

// ---- prep B: gather weight[sample_ids] -> bf16 [NSAMPLED][NHID]; colconst ----
__global__ void k_prep_b(const float* __restrict__ weight, const int* __restrict__ sid,
                         const float* __restrict__ sfreq, const float* __restrict__ bias,
                         u16* __restrict__ outB, float* __restrict__ colconst) {
  int t = threadIdx.x;
  int r = blockIdx.x * 8 + (t >> 5);  // 8 rows per 256-thread block
  int l = t & 31;                     // 32 lanes per row, 8 elems each
  int s = sid[r];
  const float* src = weight + (size_t)s * NHID + l * 8;
  float4 v0 = ((const float4*)src)[0];
  float4 v1 = ((const float4*)src)[1];
  *(s16x8*)(outB + (size_t)r * NHID + l * 8) = pack8(v0, v1);
  if (l == 0) colconst[r] = bias[s] - sfreq[r];
}

// ---- true logits (col 0) + zero the int32 new_targets tail ----
__global__ void k_true(const float* __restrict__ inputs, const int* __restrict__ labels,
                       const float* __restrict__ tfreq, const float* __restrict__ weight,
                       const float* __restrict__ bias, float* __restrict__ out) {
  int w = threadIdx.x >> 6, lane = threadIdx.x & 63;
  int b = blockIdx.x * 4 + w;
  int lab = labels[b];
  const float4 x = *(const float4*)(inputs + (size_t)b * NHID + lane * 4);
  const float4 ww = *(const float4*)(weight + (size_t)lab * NHID + lane * 4);
  float s = x.x * ww.x + x.y * ww.y + x.z * ww.z + x.w * ww.w;
  #pragma unroll
  for (int off = 32; off; off >>= 1) s += __shfl_down(s, off, 64);
  if (lane == 0) out[(size_t)b * LROW] = s + bias[lab] - tfreq[b];
  int tid = blockIdx.x * 256 + threadIdx.x;
  if (tid < BATCH) out[OUT_TAIL + tid] = 0.0f;  // int32 zeros == fp32 0.0 bits
}

// ---- main GEMM: C[b][s] = sum_k A[b][k]*B[s][k] + colconst[s] ----
// 128x128 tile, BK=128 x2, 4 waves of 64x64, mfma 16x16x32 bf16.
// LDS 64KB -> 2 blocks/CU. XOR swizzle (chunk ^= row&7) kills the 16-way
// bank conflict of the 256B-row layout; applied on BOTH write and read.
__global__ __launch_bounds__(256, 2) void k_gemm(const u16* __restrict__ A,
                                                 const u16* __restrict__ B,
                                                 const float* __restrict__ colconst,
                                                 float* __restrict__ out) {
  __shared__ u16 lA[128 * 128];
  __shared__ u16 lB[128 * 128];
  int t = threadIdx.x;
  int lane = t & 63;
  int w = t >> 6;
  // XCD-aware swizzle: 4096 blocks, 4096 % 8 == 0 -> simple variant bijective
  int bid = blockIdx.x;
  int swz = (bid & 7) * 512 + (bid >> 3);
  int brow = swz >> 6;
  int bcol = swz & 63;
  int wr = w >> 1, wc = w & 1;
  const int l15 = lane & 15;
  const int lhi = lane >> 4;

  f32x4 acc[4][4];
  #pragma unroll
  for (int i = 0; i < 4; ++i)
    #pragma unroll
    for (int j = 0; j < 4; ++j) acc[i][j] = (f32x4){0.f, 0.f, 0.f, 0.f};

  for (int kt = 0; kt < 2; ++kt) {
    // stage: 2048 16B-chunks per matrix, 8 iters x 256 threads
    #pragma unroll
    for (int i = 0; i < 8; ++i) {
      int chunk = i * 256 + t;
      int row = chunk >> 4;       // 16 chunks per 128-bf16 row
      int c = chunk & 15;         // linear LDS position
      int cs = c ^ (row & 7);     // swizzled source chunk (involution)
      s16x8 va = *(const s16x8*)(A + (size_t)(brow * 128 + row) * NHID + kt * 128 + cs * 8);
      s16x8 vb = *(const s16x8*)(B + (size_t)(bcol * 128 + row) * NHID + kt * 128 + cs * 8);
      *(s16x8*)(lA + row * 128 + c * 8) = va;
      *(s16x8*)(lB + row * 128 + c * 8) = vb;
    }
    __syncthreads();
    #pragma unroll
    for (int k0 = 0; k0 < 4; ++k0) {
      int kc = k0 * 4 + lhi;  // 16B-chunk index along K
      s16x8 af[4], bfr[4];
      #pragma unroll
      for (int mi = 0; mi < 4; ++mi) {
        int row = wr * 64 + mi * 16 + l15;
        af[mi] = *(const s16x8*)(lA + row * 128 + ((kc ^ (row & 7)) * 8));
      }
      #pragma unroll
      for (int ni = 0; ni < 4; ++ni) {
        int row = wc * 64 + ni * 16 + l15;
        bfr[ni] = *(const s16x8*)(lB + row * 128 + ((kc ^ (row & 7)) * 8));
      }
      #pragma unroll
      for (int mi = 0; mi < 4; ++mi)
        #pragma unroll
        for (int ni = 0; ni < 4; ++ni)
          acc[mi][ni] = __builtin_amdgcn_mfma_f32_16x16x32_bf16(af[mi], bfr[ni], acc[mi][ni], 0, 0, 0);
    }
    __syncthreads();
  }

  // epilogue: + colconst, dword scatter into stride-8193 rows (col 0 is true logit)
  int grow0 = brow * 128 + wr * 64;
  int gcol0 = bcol * 128 + wc * 64;
  float cc[4];
  #pragma unroll
  for (int ni = 0; ni < 4; ++ni) cc[ni] = colconst[gcol0 + ni * 16 + l15];
  #pragma unroll
  for (int mi = 0; mi < 4; ++mi) {
    #pragma unroll
    for (int r = 0; r < 4; ++r) {
      size_t rbase = (size_t)(grow0 + mi * 16 + lhi * 4 + r) * LROW + 1;
      #pragma unroll
      for (int ni = 0; ni < 4; ++ni)
        out[rbase + gcol0 + ni * 16 + l15] = acc[mi][ni][r] + cc[ni];
    }
  }
}

extern "C" void kernel_launch(void* const* d_in, const int* in_sizes, int n_in,
                              void* d_out, int out_size, void* d_ws, size_t ws_size,
                              hipStream_t stream) {
  const float* inputs          = (const float*)d_in[0];
  const int*   labels          = (const int*)d_in[1];
  const int*   sample_ids      = (const int*)d_in[2];
  const float* true_log_freq   = (const float*)d_in[3];
  const float* sample_log_freq = (const float*)d_in[4];
  const float* weight          = (const float*)d_in[5];
  const float* bias            = (const float*)d_in[6];
  float* out = (float*)d_out;

  u16* wsA = (u16*)d_ws;                               // 4 MB
  u16* wsB = wsA + (size_t)BATCH * NHID;               // 4 MB
  float* colconst = (float*)(wsB + (size_t)NSAMPLED * NHID);  // 32 KB

  hipLaunchKernelGGL(k_prep_a, dim3(BATCH * NHID / 2048), dim3(256), 0, stream, inputs, wsA);
  hipLaunchKernelGGL(k_prep_b, dim3(NSAMPLED / 8), dim3(256), 0, stream,
                     weight, sample_ids, sample_log_freq, bias, wsB, colconst);
  hipLaunchKernelGGL(k_true, dim3(BATCH / 4), dim3(256), 0, stream,
                     inputs, labels, true_log_freq, weight, bias, out);
  hipLaunchKernelGGL(k_gemm, dim3(64 * 64), dim3(256), 0, stream, wsA, wsB, colconst, out);
}

// Round 2
// 93.015 us; speedup vs baseline: 1.1537x; 1.1537x over previous
//
#include <hip/hip_runtime.h>
#include <hip/hip_bf16.h>

#define NTOKENS 500000
#define NSAMPLED 8192
#define NHID 256
#define BATCH 8192
#define LROW 8193  // 1 + NSAMPLED
#define OUT_TAIL ((size_t)BATCH * LROW)

typedef short s16x8 __attribute__((ext_vector_type(8)));
typedef float f32x4 __attribute__((ext_vector_type(4)));
typedef unsigned short u16;

// RNE float->bf16
static __device__ __forceinline__ u16 f2bf(float f) {
  unsigned u = __float_as_uint(f);
  return (u16)((u + 0x7fffu + ((u >> 16) & 1u)) >> 16);
}

static __device__ __forceinline__ s16x8 pack8(float4 v0, float4 v1) {
  s16x8 o;
  o[0] = (short)f2bf(v0.x); o[1] = (short)f2bf(v0.y);
  o[2] = (short)f2bf(v0.z); o[3] = (short)f2bf(v0.w);
  o[4] = (short)f2bf(v1.x); o[5] = (short)f2bf(v1.y);
  o[6] = (short)f2bf(v1.z); o[7] = (short)f2bf(v1.w);
  return o;
}

static __device__ __forceinline__ void gload_lds16(const void* g, void* l) {
  __builtin_amdgcn_global_load_lds(
      (const __attribute__((address_space(1))) void*)g,
      (__attribute__((address_space(3))) void*)l, 16, 0, 0);
}

// ---- fused prep: [0,1024) A->bf16 | [1024,2048) gather B->bf16 + colconst
//                  | [2048,4096) true logits + zero targets ----
__global__ void k_prep(const float* __restrict__ inputs, const int* __restrict__ labels,
                       const int* __restrict__ sample_ids, const float* __restrict__ tfreq,
                       const float* __restrict__ sfreq, const float* __restrict__ weight,
                       const float* __restrict__ bias, u16* __restrict__ outA,
                       u16* __restrict__ outB, float* __restrict__ colconst,
                       float* __restrict__ out) {
  int bid = blockIdx.x;
  int t = threadIdx.x;
  if (bid < 1024) {                       // inputs fp32 -> bf16 [BATCH][NHID]
    size_t idx = ((size_t)bid * 256 + t) * 8;
    const float4* p = (const float4*)(inputs + idx);
    *(s16x8*)(outA + idx) = pack8(p[0], p[1]);
  } else if (bid < 2048) {                // gather weight[sample_ids] -> bf16; colconst
    int r = (bid - 1024) * 8 + (t >> 5);
    int l = t & 31;
    int s = sample_ids[r];
    const float* src = weight + (size_t)s * NHID + l * 8;
    *(s16x8*)(outB + (size_t)r * NHID + l * 8) =
        pack8(((const float4*)src)[0], ((const float4*)src)[1]);
    if (l == 0) colconst[r] = bias[s] - sfreq[r];
  } else {                                // true logits (col 0) + int32 zeros tail
    int bb = bid - 2048;
    int w = t >> 6, lane = t & 63;
    int b = bb * 4 + w;
    int lab = labels[b];
    const float4 x = *(const float4*)(inputs + (size_t)b * NHID + lane * 4);
    const float4 ww = *(const float4*)(weight + (size_t)lab * NHID + lane * 4);
    float s = x.x * ww.x + x.y * ww.y + x.z * ww.z + x.w * ww.w;
    #pragma unroll
    for (int off = 32; off; off >>= 1) s += __shfl_down(s, off, 64);
    if (lane == 0) out[(size_t)b * LROW] = s + bias[lab] - tfreq[b];
    int tid = bb * 256 + t;
    if (tid < BATCH) out[OUT_TAIL + tid] = 0.0f;
  }
}

// ---- GEMM: C[b][s] = sum_k A[b][k]*B[s][k] + colconst[s] ----
// 128x128 tile, BK=64 x4 steps, single-buffered 32KB LDS -> 4 blocks/CU so
// store/compute/stage phases interleave across blocks (write-duty-cycle fix).
// Staging via global_load_lds(16B): linear LDS dest + XOR-pre-swizzled global
// source (rule #21); fragment reads apply the same XOR -> ~2-way conflicts.
__global__ __launch_bounds__(256, 4) void k_gemm(const u16* __restrict__ A,
                                                 const u16* __restrict__ B,
                                                 const float* __restrict__ colconst,
                                                 float* __restrict__ out) {
  __shared__ u16 lA[128 * 64];
  __shared__ u16 lB[128 * 64];
  int t = threadIdx.x;
  int lane = t & 63;
  int w = t >> 6;
  // XCD rectangle swizzle: xcd = bid&7 (round-robin dispatch) gets a 32x16
  // (brow x bcol) rectangle -> L2 footprint 2MB A + 1MB B < 4MiB per XCD.
  int bid = blockIdx.x;
  int xcd = bid & 7, idx = bid >> 3;
  int brow = (xcd >> 2) * 32 + (idx >> 4);
  int bcol = (xcd & 3) * 16 + (idx & 15);
  int wr = w >> 1, wc = w & 1;
  const int l15 = lane & 15;
  const int lhi = lane >> 4;

  f32x4 acc[4][4];
  #pragma unroll
  for (int i = 0; i < 4; ++i)
    #pragma unroll
    for (int j = 0; j < 4; ++j) acc[i][j] = (f32x4){0.f, 0.f, 0.f, 0.f};

  const u16* Abase = A + (size_t)brow * 128 * NHID;
  const u16* Bbase = B + (size_t)bcol * 128 * NHID;

  for (int kt = 0; kt < 4; ++kt) {
    // stage 16KB A + 16KB B: per wave 4+4 global_load_lds (64 lanes x 16B each)
    #pragma unroll
    for (int i = 0; i < 4; ++i) {
      int chunk = (w * 4 + i) * 64 + lane;  // 0..1023 16B-chunks per tile
      int row = chunk >> 3;                 // 8 chunks per 64-elem row
      int cs = (chunk & 7) ^ (row & 7);     // pre-swizzled source chunk
      const u16* ga = Abase + (size_t)row * NHID + kt * 64 + cs * 8;
      const u16* gb = Bbase + (size_t)row * NHID + kt * 64 + cs * 8;
      gload_lds16(ga, lA + (w * 4 + i) * 512);
      gload_lds16(gb, lB + (w * 4 + i) * 512);
    }
    __syncthreads();
    #pragma unroll
    for (int ks = 0; ks < 2; ++ks) {
      int kc = ks * 4 + lhi;  // 16B-chunk index along the 64-elem row
      s16x8 af[4], bfr[4];
      #pragma unroll
      for (int mi = 0; mi < 4; ++mi) {
        int row = wr * 64 + mi * 16 + l15;
        af[mi] = *(const s16x8*)(lA + row * 64 + ((kc ^ (row & 7)) * 8));
      }
      #pragma unroll
      for (int ni = 0; ni < 4; ++ni) {
        int row = wc * 64 + ni * 16 + l15;
        bfr[ni] = *(const s16x8*)(lB + row * 64 + ((kc ^ (row & 7)) * 8));
      }
      #pragma unroll
      for (int mi = 0; mi < 4; ++mi)
        #pragma unroll
        for (int ni = 0; ni < 4; ++ni)
          acc[mi][ni] = __builtin_amdgcn_mfma_f32_16x16x32_bf16(af[mi], bfr[ni], acc[mi][ni], 0, 0, 0);
    }
    __syncthreads();
  }

  // epilogue: + colconst, dword stores into stride-8193 rows (col 0 = true logit)
  int grow0 = brow * 128 + wr * 64;
  int gcol0 = bcol * 128 + wc * 64;
  float cc[4];
  #pragma unroll
  for (int ni = 0; ni < 4; ++ni) cc[ni] = colconst[gcol0 + ni * 16 + l15];
  #pragma unroll
  for (int mi = 0; mi < 4; ++mi) {
    #pragma unroll
    for (int r = 0; r < 4; ++r) {
      size_t rbase = (size_t)(grow0 + mi * 16 + lhi * 4 + r) * LROW + 1;
      #pragma unroll
      for (int ni = 0; ni < 4; ++ni)
        out[rbase + gcol0 + ni * 16 + l15] = acc[mi][ni][r] + cc[ni];
    }
  }
}

extern "C" void kernel_launch(void* const* d_in, const int* in_sizes, int n_in,
                              void* d_out, int out_size, void* d_ws, size_t ws_size,
                              hipStream_t stream) {
  const float* inputs          = (const float*)d_in[0];
  const int*   labels          = (const int*)d_in[1];
  const int*   sample_ids      = (const int*)d_in[2];
  const float* true_log_freq   = (const float*)d_in[3];
  const float* sample_log_freq = (const float*)d_in[4];
  const float* weight          = (const float*)d_in[5];
  const float* bias            = (const float*)d_in[6];
  float* out = (float*)d_out;

  u16* wsA = (u16*)d_ws;                                      // 4 MB
  u16* wsB = wsA + (size_t)BATCH * NHID;                      // 4 MB
  float* colconst = (float*)(wsB + (size_t)NSAMPLED * NHID);  // 32 KB

  hipLaunchKernelGGL(k_prep, dim3(4096), dim3(256), 0, stream,
                     inputs, labels, sample_ids, true_log_freq, sample_log_freq,
                     weight, bias, wsA, wsB, colconst, out);
  hipLaunchKernelGGL(k_gemm, dim3(64 * 64), dim3(256), 0, stream, wsA, wsB, colconst, out);
}